// Round 5
// baseline (361.052 us; speedup 1.0000x reference)
//
#include <hip/hip_runtime.h>
#include <math.h>

#define NCV   30000
#define NX    60000
#define NM    8
#define LN_EPSF 1e-5f
#define NFORCE 9000000      // force floats (3M x 3); d_out = [energy, forces...]

#define NBLK  256           // 1 block per CU -> co-residency guaranteed
#define JBZ   59            // z0 slabs of 1024 rows
#define Z0_ITEMS (NM*JBZ)   // 472
#define NBX   235           // bwdx 256-row items per model
#define BW_ITEMS (NM*NBX)   // 1880

// ---------------- workspace layout (float offsets) ----------------
#define WS_XRAW   0          // 60000  (cos | sin)
#define WS_DCV    60000      // 360000 dphi/dx TRANSPOSED [12][30000]
#define WS_G      420000     // 480000 dE/dxhat*gamma per model (8 x 60000)
#define WS_LNP    900000     // 512: [256 sum_x | 256 sum_x2]
#define WS_Z0P    900512     // 472*64 z0 partials
#define WS_DZ0    930720     // 512
#define WS_E      931232     // 8
#define WS_SGP    931240     // 1880
#define WS_SGXP   933120     // 1880
#define WS_CTRL   935008     // 12 words: u[0..3] barcnt, u[4..7] barflag, u[8] ticket, u[9] sigflag, f[10] varsum, f[11] sigma

struct F3 { float x, y, z; };
__device__ __forceinline__ F3 f3sub(F3 a, F3 b){ return {a.x-b.x, a.y-b.y, a.z-b.z}; }
__device__ __forceinline__ F3 f3add(F3 a, F3 b){ return {a.x+b.x, a.y+b.y, a.z+b.z}; }
__device__ __forceinline__ F3 f3scale(F3 a, float s){ return {a.x*s, a.y*s, a.z*s}; }
__device__ __forceinline__ float f3dot(F3 a, F3 b){ return a.x*b.x + a.y*b.y + a.z*b.z; }
__device__ __forceinline__ F3 f3cross(F3 a, F3 b){
  return { a.y*b.z - a.z*b.y, a.z*b.x - a.x*b.z, a.x*b.y - a.y*b.x };
}

union Smem {
  struct { float stats[2]; float yl[1024]; float red[4][16][4]; } z0;
  struct { float Wl[3][64*65]; float hs[4][64]; float part[256]; float ds[64]; } mlp;
  struct { float dz[64]; float sa[4], sb[4]; } bw;
  struct { float sSg[NM], sSgx[NM]; float sv[4]; float ssig; } mf;
  struct { float sa[4], sb[4]; } cv;
};

// device-wide barrier: proven ticket/flag pattern (agent-scope, fence-chained)
__device__ __forceinline__ void gbar(unsigned* cnt, unsigned* flag) {
  __syncthreads();
  if (threadIdx.x == 0) {
    __threadfence();
    unsigned old = atomicAdd(cnt, 1u);
    if (old == NBLK - 1)
      __hip_atomic_store(flag, 1u, __ATOMIC_RELEASE, __HIP_MEMORY_SCOPE_AGENT);
    while (__hip_atomic_load(flag, __ATOMIC_ACQUIRE, __HIP_MEMORY_SCOPE_AGENT) == 0u)
      __builtin_amdgcn_s_sleep(2);
    __threadfence();
  }
  __syncthreads();
}

__global__ void k_init(float* __restrict__ ws) {
  if (threadIdx.x < 12) ((unsigned*)(ws + WS_CTRL))[threadIdx.x] = 0u;
}

__global__ __launch_bounds__(256, 1)
void k_mega(const float* __restrict__ pos, const float* __restrict__ box,
            const int* __restrict__ idx, const float* __restrict__ gamma,
            const float* __restrict__ beta,
            const float4* __restrict__ W0, const float* __restrict__ b0,
            const float* __restrict__ W1, const float* __restrict__ b1,
            const float* __restrict__ W2, const float* __restrict__ b2,
            const float* __restrict__ W3, const float* __restrict__ b3,
            const float* __restrict__ W4, const float* __restrict__ b4,
            float* __restrict__ ws, float* __restrict__ out) {
  __shared__ Smem sm;
  int tid = threadIdx.x;
  int bid = blockIdx.x;
  int w = tid >> 6, l = tid & 63;
  unsigned* wu = (unsigned*)(ws + WS_CTRL);

  // ================= P0: zero forces + dihedrals + LN partials =================
  {
    int gtid = bid * 256 + tid;
    float4 z4 = {0.f, 0.f, 0.f, 0.f};
    float4* fz = (float4*)(out + 4);
    const int NF4 = (NFORCE - 4) / 4;
    for (int i = gtid; i < NF4; i += NBLK * 256) fz[i] = z4;
    if (gtid == 0) { out[1] = 0.f; out[2] = 0.f; out[3] = 0.f; out[NFORCE] = 0.f; }

    float cx = 0.f, cx2 = 0.f;
    int i = gtid;
    if (i < NCV) {
      float bx = box[0], by = box[4], bz = box[8];
      int4 q4 = *(const int4*)(idx + i*4);
      int pidx[4] = {q4.x, q4.y, q4.z, q4.w};
      F3 p[4];
      #pragma unroll
      for (int a = 0; a < 4; a++) {
        int pi = pidx[a];
        float X = pos[(size_t)pi*3 + 0];
        float Y = pos[(size_t)pi*3 + 1];
        float Z = pos[(size_t)pi*3 + 2];
        X -= floorf(X / bx) * bx;
        Y -= floorf(Y / by) * by;
        Z -= floorf(Z / bz) * bz;
        p[a] = {X, Y, Z};
      }
      F3 b1v = f3sub(p[1], p[0]);
      F3 b2v = f3sub(p[2], p[1]);
      F3 b3v = f3sub(p[3], p[2]);
      F3 n1 = f3cross(b1v, b2v);
      F3 n2 = f3cross(b2v, b3v);
      float L = sqrtf(f3dot(b2v, b2v));
      F3 u = f3scale(b2v, 1.f / L);
      F3 m1 = f3cross(n1, u);
      float yv = f3dot(m1, n2);
      float xv = f3dot(n1, n2);
      float h = sqrtf(xv*xv + yv*yv);
      float cphi = xv / h;
      float sphi = yv / h;

      float invd = 1.f / (h*h);
      float dX = -yv * invd;
      float dY =  xv * invd;
      F3 dn1 = f3scale(n2, dX);
      F3 dn2 = f3scale(n1, dX);
      F3 dm1 = f3scale(n2, dY);
      dn2 = f3add(dn2, f3scale(m1, dY));
      dn1 = f3add(dn1, f3cross(u, dm1));
      F3 du = f3cross(dm1, n1);
      float ud = f3dot(u, du);
      F3 db2 = f3scale(f3sub(du, f3scale(u, ud)), 1.f / L);
      db2 = f3add(db2, f3cross(b3v, dn2));
      F3 db3 = f3cross(dn2, b2v);
      F3 db1 = f3cross(b2v, dn1);
      db2 = f3add(db2, f3cross(dn1, b1v));

      F3 g0 = f3scale(db1, -1.f);
      F3 g1 = f3sub(db1, db2);
      F3 g2 = f3sub(db2, db3);
      F3 g3 = db3;

      ws[WS_XRAW + i]       = cphi;
      ws[WS_XRAW + NCV + i] = sphi;
      ws[WS_DCV + 0*NCV  + i] = g0.x; ws[WS_DCV + 1*NCV  + i] = g0.y; ws[WS_DCV + 2*NCV  + i] = g0.z;
      ws[WS_DCV + 3*NCV  + i] = g1.x; ws[WS_DCV + 4*NCV  + i] = g1.y; ws[WS_DCV + 5*NCV  + i] = g1.z;
      ws[WS_DCV + 6*NCV  + i] = g2.x; ws[WS_DCV + 7*NCV  + i] = g2.y; ws[WS_DCV + 8*NCV  + i] = g2.z;
      ws[WS_DCV + 9*NCV  + i] = g3.x; ws[WS_DCV + 10*NCV + i] = g3.y; ws[WS_DCV + 11*NCV + i] = g3.z;

      cx  = cphi + sphi;
      cx2 = cphi*cphi + sphi*sphi;
    }
    #pragma unroll
    for (int o = 1; o < 64; o <<= 1) { cx += __shfl_xor(cx, o); cx2 += __shfl_xor(cx2, o); }
    if (l == 0) { sm.cv.sa[w] = cx; sm.cv.sb[w] = cx2; }
    __syncthreads();
    if (tid == 0) {
      ws[WS_LNP + bid]        = sm.cv.sa[0] + sm.cv.sa[1] + sm.cv.sa[2] + sm.cv.sa[3];
      ws[WS_LNP + NBLK + bid] = sm.cv.sb[0] + sm.cv.sb[1] + sm.cv.sb[2] + sm.cv.sb[3];
    }
  }

  gbar(wu + 0, wu + 4);

  // ================= mu / inv (into registers, all blocks) =================
  float mu, inv;
  {
    if (tid < 64) {
      float a = 0.f, b = 0.f;
      #pragma unroll
      for (int k = tid; k < NBLK; k += 64) { a += ws[WS_LNP + k]; b += ws[WS_LNP + NBLK + k]; }
      #pragma unroll
      for (int o = 1; o < 64; o <<= 1) { a += __shfl_xor(a, o); b += __shfl_xor(b, o); }
      if (tid == 0) {
        float mu_  = a * (1.f / NX);
        float var = b * (1.f / NX) - mu_ * mu_;
        sm.z0.stats[0] = mu_;
        sm.z0.stats[1] = 1.f / sqrtf(var + LN_EPSF);
      }
    }
    __syncthreads();
    mu = sm.z0.stats[0]; inv = sm.z0.stats[1];
  }

  // ================= P1: z0 partials (1024-row slabs, R2 access pattern) =================
  for (int item = bid; item < Z0_ITEMS; item += NBLK) {
    int m = item / JBZ, jb = item - m * JBZ;
    int j0 = jb * 1024;
    __syncthreads();
    for (int jj = tid; jj < 1024; jj += 256) {
      int gj = j0 + jj;
      sm.z0.yl[jj] = (gj < NX) ? ((ws[WS_XRAW + gj] - mu) * inv * gamma[gj] + beta[gj]) : 0.f;
    }
    __syncthreads();
    int k4 = tid & 15, r = tid >> 4;
    const float4* Wm = W0 + (size_t)m * NX * 16;
    float4 acc = {0.f, 0.f, 0.f, 0.f};
    #pragma unroll 4
    for (int j = r; j < 1024; j += 16) {
      int gj = j0 + j;
      if (gj < NX) {
        float y = sm.z0.yl[j];
        float4 wv = Wm[(size_t)gj * 16 + k4];
        acc.x += y * wv.x; acc.y += y * wv.y; acc.z += y * wv.z; acc.w += y * wv.w;
      }
    }
    #pragma unroll
    for (int o = 16; o <= 32; o <<= 1) {
      acc.x += __shfl_xor(acc.x, o); acc.y += __shfl_xor(acc.y, o);
      acc.z += __shfl_xor(acc.z, o); acc.w += __shfl_xor(acc.w, o);
    }
    if (l < 16) {
      sm.z0.red[w][l][0] = acc.x; sm.z0.red[w][l][1] = acc.y;
      sm.z0.red[w][l][2] = acc.z; sm.z0.red[w][l][3] = acc.w;
    }
    __syncthreads();
    if (tid < 64) {
      int kk4 = tid & 15, c = tid >> 4;
      float v = sm.z0.red[0][kk4][c] + sm.z0.red[1][kk4][c] +
                sm.z0.red[2][kk4][c] + sm.z0.red[3][kk4][c];
      ws[WS_Z0P + (size_t)item * 64 + kk4 * 4 + c] = v;
    }
  }

  gbar(wu + 1, wu + 5);

  // ================= P2: tiny MLP fwd+bwd (blocks 0..7) =================
  if (bid < NM) {
    int m = bid;
    int k = tid & 63, q = tid >> 6;
    const float* Wsrc0 = W1 + m*4096;
    const float* Wsrc1 = W2 + m*4096;
    const float* Wsrc2 = W3 + m*4096;
    for (int e = tid; e < 4096; e += 256) {
      int t = e >> 6, kk = e & 63;
      sm.mlp.Wl[0][t*65 + kk] = Wsrc0[e];
      sm.mlp.Wl[1][t*65 + kk] = Wsrc1[e];
      sm.mlp.Wl[2][t*65 + kk] = Wsrc2[e];
    }
    float p0 = 0.f;
    for (int jb = q; jb < JBZ; jb += 4)
      p0 += ws[WS_Z0P + (size_t)(m * JBZ + jb) * 64 + k];
    sm.mlp.part[tid] = p0;
    __syncthreads();
    if (tid < 64) {
      float a0 = b0[m*64 + k] + sm.mlp.part[k] + sm.mlp.part[64+k] + sm.mlp.part[128+k] + sm.mlp.part[192+k];
      sm.mlp.hs[0][k] = fmaxf(a0, 0.f);
    }
    __syncthreads();
    #pragma unroll
    for (int ll = 0; ll < 3; ll++) {
      float pp = 0.f;
      #pragma unroll
      for (int t0 = 0; t0 < 16; t0++) {
        int t = q*16 + t0;
        pp += sm.mlp.hs[ll][t] * sm.mlp.Wl[ll][t*65 + k];
      }
      sm.mlp.part[tid] = pp;
      __syncthreads();
      if (tid < 64) {
        const float* bl = (ll==0) ? b1 : (ll==1) ? b2 : b3;
        float a = bl[m*64+k] + sm.mlp.part[k] + sm.mlp.part[64+k] + sm.mlp.part[128+k] + sm.mlp.part[192+k];
        sm.mlp.hs[ll+1][k] = fmaxf(a, 0.f);
      }
      __syncthreads();
    }
    if (tid < 64) {
      float w4k = W4[m*64 + k];
      float e = sm.mlp.hs[3][k] * w4k;
      #pragma unroll
      for (int o = 1; o < 64; o <<= 1) e += __shfl_xor(e, o);
      if (k == 0) ws[WS_E + m] = e + b4[m];
      sm.mlp.ds[k] = (sm.mlp.hs[3][k] > 0.f) ? w4k : 0.f;
    }
    __syncthreads();
    #pragma unroll
    for (int ll = 2; ll >= 0; ll--) {
      float pp = 0.f;
      int t = k;
      #pragma unroll
      for (int k0 = 0; k0 < 16; k0++) {
        int kk = q*16 + k0;
        pp += sm.mlp.Wl[ll][t*65 + kk] * sm.mlp.ds[kk];
      }
      sm.mlp.part[tid] = pp;
      __syncthreads();
      if (tid < 64) {
        float dh = sm.mlp.part[k] + sm.mlp.part[64+k] + sm.mlp.part[128+k] + sm.mlp.part[192+k];
        float dz = (sm.mlp.hs[ll][k] > 0.f) ? dh : 0.f;
        if (ll == 0) ws[WS_DZ0 + m*64 + k] = dz;
        else         sm.mlp.ds[k] = dz;
      }
      __syncthreads();
    }
  }

  gbar(wu + 2, wu + 6);

  // ================= P3: bwdx g = (W0 . dz0) * gamma + LN-bwd partials =================
  for (int item = bid; item < BW_ITEMS; item += NBLK) {
    int m = item / NBX, blk = item - m * NBX;
    __syncthreads();
    if (tid < 64) sm.bw.dz[tid] = ws[WS_DZ0 + m*64 + tid];
    __syncthreads();
    int c = tid & 15, g = tid >> 4;
    float4 d4 = ((const float4*)sm.bw.dz)[c];
    float sg = 0.f, sgx = 0.f;
    #pragma unroll
    for (int it = 0; it < 4; it++) {
      int jbase = blk * 256 + it * 64 + g;
      float4 wv[4];
      #pragma unroll
      for (int u = 0; u < 4; u++) {
        int j = jbase + u * 16;
        if (j < NX) wv[u] = W0[((size_t)m * NX + j) * 16 + c];
        else        wv[u] = {0.f, 0.f, 0.f, 0.f};
      }
      #pragma unroll
      for (int u = 0; u < 4; u++) {
        int j = jbase + u * 16;
        float dot = wv[u].x*d4.x + wv[u].y*d4.y + wv[u].z*d4.z + wv[u].w*d4.w;
        #pragma unroll
        for (int o = 1; o < 16; o <<= 1) dot += __shfl_xor(dot, o);
        if (c == 0 && j < NX) {
          float gg = dot * gamma[j];
          ws[WS_G + (size_t)m * NX + j] = gg;
          float xh = (ws[WS_XRAW + j] - mu) * inv;
          sg += gg; sgx += gg * xh;
        }
      }
    }
    #pragma unroll
    for (int o = 1; o < 64; o <<= 1) { sg += __shfl_xor(sg, o); sgx += __shfl_xor(sgx, o); }
    if (l == 0) { sm.bw.sa[w] = sg; sm.bw.sb[w] = sgx; }
    __syncthreads();
    if (tid == 0) {
      ws[WS_SGP  + item] = sm.bw.sa[0] + sm.bw.sa[1] + sm.bw.sa[2] + sm.bw.sa[3];
      ws[WS_SGXP + item] = sm.bw.sb[0] + sm.bw.sb[1] + sm.bw.sb[2] + sm.bw.sb[3];
    }
  }

  gbar(wu + 3, wu + 7);

  // ================= P4: mean force + variance + sigma + scatter =================
  {
    for (int m = w; m < NM; m += 4) {
      float a = 0.f, b = 0.f;
      #pragma unroll 2
      for (int bb = l; bb < NBX; bb += 64) { a += ws[WS_SGP + m*NBX + bb]; b += ws[WS_SGXP + m*NBX + bb]; }
      #pragma unroll
      for (int o = 1; o < 64; o <<= 1) { a += __shfl_xor(a, o); b += __shfl_xor(b, o); }
      if (l == 0) { sm.mf.sSg[m] = a * (1.f / NX); sm.mf.sSgx[m] = b * (1.f / NX); }
    }
    __syncthreads();

    int i = bid * 256 + tid;
    float v = 0.f, fm = 0.f;
    if (i < NCV) {
      float cph = ws[WS_XRAW + i], sph = ws[WS_XRAW + NCV + i];
      float xc = (cph - mu) * inv, xs = (sph - mu) * inv;
      float f[NM];
      #pragma unroll
      for (int m = 0; m < NM; m++) {
        float gc = ws[WS_G + (size_t)m * NX + i];
        float gs = ws[WS_G + (size_t)m * NX + NCV + i];
        float dxc = inv * (gc - sm.mf.sSg[m] - xc * sm.mf.sSgx[m]);
        float dxs = inv * (gs - sm.mf.sSg[m] - xs * sm.mf.sSgx[m]);
        float dE = dxc * (-sph) + dxs * cph;
        f[m] = -dE;
        fm += f[m];
      }
      fm *= (1.f / NM);
      float acc = 0.f;
      #pragma unroll
      for (int m = 0; m < NM; m++) { float d = f[m] - fm; acc += d * d; }
      v = acc * (1.f / (NM - 1));
    }
    #pragma unroll
    for (int o = 1; o < 64; o <<= 1) v += __shfl_xor(v, o);
    if (l == 0) sm.mf.sv[w] = v;
    __syncthreads();
    if (tid == 0) {
      float* varsum = ws + WS_CTRL + 10;
      float* sigp   = ws + WS_CTRL + 11;
      atomicAdd(varsum, sm.mf.sv[0] + sm.mf.sv[1] + sm.mf.sv[2] + sm.mf.sv[3]);
      __threadfence();
      unsigned old = atomicAdd(wu + 8, 1u);
      if (old == NBLK - 1) {
        float tot = atomicAdd(varsum, 0.0f);
        float md = sqrtf(tot * (1.f / NCV));
        float isw = (3.0f - md) / (3.0f - 2.0f);
        float fl = floorf(isw);
        float smooth = 0.5f * (1.f + cosf(3.14159265358979323846f * (1.f - isw)));
        float sigma = (fl > 0.f) ? 1.f : ((fl < 0.f) ? 0.f : smooth);
        float em = 0.f;
        #pragma unroll
        for (int m = 0; m < NM; m++) em += ws[WS_E + m];
        em *= (1.f / NM);
        out[0] = em * sigma;
        __hip_atomic_store(sigp, sigma, __ATOMIC_RELAXED, __HIP_MEMORY_SCOPE_AGENT);
        __hip_atomic_store(wu + 9, 1u, __ATOMIC_RELEASE, __HIP_MEMORY_SCOPE_AGENT);
      }
      while (__hip_atomic_load(wu + 9, __ATOMIC_ACQUIRE, __HIP_MEMORY_SCOPE_AGENT) == 0u)
        __builtin_amdgcn_s_sleep(2);
      sm.mf.ssig = __hip_atomic_load(ws + WS_CTRL + 11, __ATOMIC_RELAXED, __HIP_MEMORY_SCOPE_AGENT);
    }
    __syncthreads();
    float sigma = sm.mf.ssig;

    if (i < NCV) {
      float d[12];
      #pragma unroll
      for (int r = 0; r < 12; r++) d[r] = ws[WS_DCV + r*NCV + i];
      int4 q4 = *(const int4*)(idx + i*4);
      float s = fm * sigma;
      float* fp = out + 1;
      atomicAdd(&fp[(size_t)q4.x*3 + 0], s*d[0]);
      atomicAdd(&fp[(size_t)q4.x*3 + 1], s*d[1]);
      atomicAdd(&fp[(size_t)q4.x*3 + 2], s*d[2]);
      atomicAdd(&fp[(size_t)q4.y*3 + 0], s*d[3]);
      atomicAdd(&fp[(size_t)q4.y*3 + 1], s*d[4]);
      atomicAdd(&fp[(size_t)q4.y*3 + 2], s*d[5]);
      atomicAdd(&fp[(size_t)q4.z*3 + 0], s*d[6]);
      atomicAdd(&fp[(size_t)q4.z*3 + 1], s*d[7]);
      atomicAdd(&fp[(size_t)q4.z*3 + 2], s*d[8]);
      atomicAdd(&fp[(size_t)q4.w*3 + 0], s*d[9]);
      atomicAdd(&fp[(size_t)q4.w*3 + 1], s*d[10]);
      atomicAdd(&fp[(size_t)q4.w*3 + 2], s*d[11]);
    }
  }
}

extern "C" void kernel_launch(void* const* d_in, const int* in_sizes, int n_in,
                              void* d_out, int out_size, void* d_ws, size_t ws_size,
                              hipStream_t stream) {
  const float* pos   = (const float*)d_in[0];
  const float* box   = (const float*)d_in[1];
  const int*   idx   = (const int*)  d_in[2];
  const float* gamma = (const float*)d_in[3];
  const float* beta  = (const float*)d_in[4];
  const float* W0 = (const float*)d_in[5];
  const float* b0 = (const float*)d_in[6];
  const float* W1 = (const float*)d_in[7];
  const float* b1 = (const float*)d_in[8];
  const float* W2 = (const float*)d_in[9];
  const float* b2 = (const float*)d_in[10];
  const float* W3 = (const float*)d_in[11];
  const float* b3 = (const float*)d_in[12];
  const float* W4 = (const float*)d_in[13];
  const float* b4 = (const float*)d_in[14];
  float* ws  = (float*)d_ws;
  float* out = (float*)d_out;

  k_init<<<1, 64, 0, stream>>>(ws);
  k_mega<<<NBLK, 256, 0, stream>>>(pos, box, idx, gamma, beta,
                                   (const float4*)W0, b0, W1, b1, W2, b2, W3, b3, W4, b4,
                                   ws, out);
}

// Round 6
// 152.581 us; speedup vs baseline: 2.3663x; 2.3663x over previous
//
#include <hip/hip_runtime.h>
#include <math.h>

#define NCV   30000
#define NX    60000
#define NM    8
#define LN_EPSF 1e-5f
#define NFORCE 9000000      // force floats (3M x 3); d_out = [energy, forces...]

#define NB_CV 512           // k_cv grid
#define JB    96            // z0 slabs per model (625 rows each; 96*625 = 60000 exactly)
#define SLAB  625
#define NBX   235           // bwdx 256-row blocks per model
#define NB_MF 118           // k_mf grid (<=256 => co-resident => spin-safe)

// ---------------- workspace layout (float offsets) ----------------
#define WS_XRAW   0          // 60000  (cos | sin)
#define WS_DCV    60000      // 360000 dphi/dx TRANSPOSED [12][30000]
#define WS_G      420000     // 480000 dE/dxhat*gamma per model (8 x 60000)
#define WS_LNP    900000     // 1024: [512 sum_x | 512 sum_x2]
#define WS_Z0P    901024     // 8*96*64 = 49152 z0 partials
#define WS_DZ0    950176     // 512
#define WS_E      950688     // 8
#define WS_SGP    950696     // 8*235 = 1880
#define WS_SGXP   952576     // 1880
#define WS_VARSUM 954456     // 1
#define WS_TICKET 954457     // 1 (uint bits)
#define WS_SIGMA  954458     // 1
#define WS_FLAG   954459     // 1 (uint bits)

struct F3 { float x, y, z; };
__device__ __forceinline__ F3 f3sub(F3 a, F3 b){ return {a.x-b.x, a.y-b.y, a.z-b.z}; }
__device__ __forceinline__ F3 f3add(F3 a, F3 b){ return {a.x+b.x, a.y+b.y, a.z+b.z}; }
__device__ __forceinline__ F3 f3scale(F3 a, float s){ return {a.x*s, a.y*s, a.z*s}; }
__device__ __forceinline__ float f3dot(F3 a, F3 b){ return a.x*b.x + a.y*b.y + a.z*b.z; }
__device__ __forceinline__ F3 f3cross(F3 a, F3 b){
  return { a.y*b.z - a.z*b.y, a.z*b.x - a.x*b.z, a.x*b.y - a.y*b.x };
}

// reduce LN per-block partials -> out2[0]=mu, out2[1]=inv_std  (wave 0 only; caller syncs)
__device__ __forceinline__ void compute_mu_inv(const float* __restrict__ ws, float* out2, int tid) {
  if (tid < 64) {
    float a = 0.f, b = 0.f;
    #pragma unroll 4
    for (int k = tid; k < NB_CV; k += 64) { a += ws[WS_LNP + k]; b += ws[WS_LNP + NB_CV + k]; }
    #pragma unroll
    for (int o = 1; o < 64; o <<= 1) { a += __shfl_xor(a, o); b += __shfl_xor(b, o); }
    if (tid == 0) {
      float mu  = a * (1.f / NX);
      float var = b * (1.f / NX) - mu * mu;
      out2[0] = mu;
      out2[1] = 1.f / sqrtf(var + LN_EPSF);
    }
  }
}

// ---------------- K1: dihedrals + grads + LN partials + zero forces ----------------
__global__ void k_cv(const float* __restrict__ pos, const float* __restrict__ box,
                     const int* __restrict__ idx, float* __restrict__ ws,
                     float* __restrict__ out) {
  int tid = threadIdx.x;
  int gtid = blockIdx.x * 256 + tid;

  // zero forces (grid-stride float4) — k_cv is latency-bound, write BW here is free (R2-verified)
  {
    float4 z4 = {0.f, 0.f, 0.f, 0.f};
    float4* fz = (float4*)(out + 4);
    const int NF4 = (NFORCE - 4) / 4;
    for (int i = gtid; i < NF4; i += NB_CV * 256) fz[i] = z4;
    if (gtid == 0) {
      out[1] = 0.f; out[2] = 0.f; out[3] = 0.f; out[NFORCE] = 0.f;
      ws[WS_VARSUM] = 0.f;
      ((unsigned int*)ws)[WS_TICKET] = 0u;
      ((unsigned int*)ws)[WS_FLAG]   = 0u;
    }
  }

  float cx = 0.f, cx2 = 0.f;
  int i = gtid;
  if (i < NCV) {
    float bx = box[0], by = box[4], bz = box[8];
    int4 q4 = *(const int4*)(idx + i*4);
    int pidx[4] = {q4.x, q4.y, q4.z, q4.w};
    F3 p[4];
    #pragma unroll
    for (int a = 0; a < 4; a++) {
      int pi = pidx[a];
      float X = pos[(size_t)pi*3 + 0];
      float Y = pos[(size_t)pi*3 + 1];
      float Z = pos[(size_t)pi*3 + 2];
      X -= floorf(X / bx) * bx;
      Y -= floorf(Y / by) * by;
      Z -= floorf(Z / bz) * bz;
      p[a] = {X, Y, Z};
    }
    F3 b1 = f3sub(p[1], p[0]);
    F3 b2 = f3sub(p[2], p[1]);
    F3 b3 = f3sub(p[3], p[2]);
    F3 n1 = f3cross(b1, b2);
    F3 n2 = f3cross(b2, b3);
    float L = sqrtf(f3dot(b2, b2));
    F3 u = f3scale(b2, 1.f / L);
    F3 m1 = f3cross(n1, u);
    float yv = f3dot(m1, n2);
    float xv = f3dot(n1, n2);
    float h = sqrtf(xv*xv + yv*yv);
    float cphi = xv / h;
    float sphi = yv / h;

    // reverse mode, dphi = 1
    float invd = 1.f / (h*h);
    float dX = -yv * invd;
    float dY =  xv * invd;
    F3 dn1 = f3scale(n2, dX);
    F3 dn2 = f3scale(n1, dX);
    F3 dm1 = f3scale(n2, dY);
    dn2 = f3add(dn2, f3scale(m1, dY));
    dn1 = f3add(dn1, f3cross(u, dm1));
    F3 du = f3cross(dm1, n1);
    float ud = f3dot(u, du);
    F3 db2 = f3scale(f3sub(du, f3scale(u, ud)), 1.f / L);
    db2 = f3add(db2, f3cross(b3, dn2));
    F3 db3 = f3cross(dn2, b2);
    F3 db1 = f3cross(b2, dn1);
    db2 = f3add(db2, f3cross(dn1, b1));

    F3 g0 = f3scale(db1, -1.f);
    F3 g1 = f3sub(db1, db2);
    F3 g2 = f3sub(db2, db3);
    F3 g3 = db3;

    ws[WS_XRAW + i]       = cphi;
    ws[WS_XRAW + NCV + i] = sphi;
    ws[WS_DCV + 0*NCV  + i] = g0.x; ws[WS_DCV + 1*NCV  + i] = g0.y; ws[WS_DCV + 2*NCV  + i] = g0.z;
    ws[WS_DCV + 3*NCV  + i] = g1.x; ws[WS_DCV + 4*NCV  + i] = g1.y; ws[WS_DCV + 5*NCV  + i] = g1.z;
    ws[WS_DCV + 6*NCV  + i] = g2.x; ws[WS_DCV + 7*NCV  + i] = g2.y; ws[WS_DCV + 8*NCV  + i] = g2.z;
    ws[WS_DCV + 9*NCV  + i] = g3.x; ws[WS_DCV + 10*NCV + i] = g3.y; ws[WS_DCV + 11*NCV + i] = g3.z;

    cx  = cphi + sphi;
    cx2 = cphi*cphi + sphi*sphi;
  }

  #pragma unroll
  for (int o = 1; o < 64; o <<= 1) { cx += __shfl_xor(cx, o); cx2 += __shfl_xor(cx2, o); }
  __shared__ float sa[4], sb[4];
  int w = tid >> 6, l = tid & 63;
  if (l == 0) { sa[w] = cx; sb[w] = cx2; }
  __syncthreads();
  if (tid == 0) {
    ws[WS_LNP + blockIdx.x]         = sa[0] + sa[1] + sa[2] + sa[3];
    ws[WS_LNP + NB_CV + blockIdx.x] = sb[0] + sb[1] + sb[2] + sb[3];
  }
}

// ---------------- K2: z0 partials; 625-row slabs, 768 equal blocks (3/CU) ----------------
__global__ void k_z0(const float4* __restrict__ W0, const float* __restrict__ gamma,
                     const float* __restrict__ beta, float* __restrict__ ws) {
  __shared__ float stats[2];
  __shared__ float yl[SLAB];
  __shared__ float red[4][16][4];
  int tid = threadIdx.x;
  int jb = blockIdx.x, m = blockIdx.y;
  int j0 = jb * SLAB;           // j0+624 <= 59999 always (96*625 = 60000)

  compute_mu_inv(ws, stats, tid);
  __syncthreads();
  float mu = stats[0], inv = stats[1];
  for (int jj = tid; jj < SLAB; jj += 256) {
    int gj = j0 + jj;
    yl[jj] = (ws[WS_XRAW + gj] - mu) * inv * gamma[gj] + beta[gj];
  }
  __syncthreads();

  int k4 = tid & 15;     // float4 column of the 64-wide row
  int r  = tid >> 4;     // row phase 0..15
  const float4* Wm = W0 + (size_t)m * NX * 16;
  float4 acc = {0.f, 0.f, 0.f, 0.f};
  for (int base = 0; base < SLAB; base += 128) {
    float4 wv[8];
    #pragma unroll
    for (int u = 0; u < 8; u++) {              // 8 independent loads in flight
      int j = base + u * 16 + r;
      if (j < SLAB) wv[u] = Wm[(size_t)(j0 + j) * 16 + k4];
    }
    #pragma unroll
    for (int u = 0; u < 8; u++) {
      int j = base + u * 16 + r;
      if (j < SLAB) {
        float y = yl[j];
        acc.x += y * wv[u].x; acc.y += y * wv[u].y;
        acc.z += y * wv[u].z; acc.w += y * wv[u].w;
      }
    }
  }
  #pragma unroll
  for (int o = 16; o <= 32; o <<= 1) {
    acc.x += __shfl_xor(acc.x, o); acc.y += __shfl_xor(acc.y, o);
    acc.z += __shfl_xor(acc.z, o); acc.w += __shfl_xor(acc.w, o);
  }
  int w = tid >> 6, l = tid & 63;
  if (l < 16) {
    red[w][l][0] = acc.x; red[w][l][1] = acc.y; red[w][l][2] = acc.z; red[w][l][3] = acc.w;
  }
  __syncthreads();
  if (tid < 64) {
    int kk4 = tid & 15, c = tid >> 4;
    float v = red[0][kk4][c] + red[1][kk4][c] + red[2][kk4][c] + red[3][kk4][c];
    ws[WS_Z0P + ((size_t)m * JB + jb) * 64 + kk4 * 4 + c] = v;
  }
}

// ---------------- K3: tiny MLP fwd+bwd per model, LDS-staged weights ----------------
__global__ void k_mlp(const float* __restrict__ ws_ro, const float* __restrict__ b0,
                      const float* __restrict__ W1, const float* __restrict__ b1,
                      const float* __restrict__ W2, const float* __restrict__ b2,
                      const float* __restrict__ W3, const float* __restrict__ b3,
                      const float* __restrict__ W4, const float* __restrict__ b4,
                      float* __restrict__ ws) {
  int m = blockIdx.x;
  int tid = threadIdx.x;
  int k = tid & 63, q = tid >> 6;           // q = t-quarter 0..3
  __shared__ float Wl[3][64*65];            // 65-stride pad: conflict-free both directions
  __shared__ float hs[4][64];
  __shared__ float part[256];
  __shared__ float ds[64];

  const float* Wsrc0 = W1 + m*4096;
  const float* Wsrc1 = W2 + m*4096;
  const float* Wsrc2 = W3 + m*4096;
  for (int e = tid; e < 4096; e += 256) {
    int t = e >> 6, kk = e & 63;
    Wl[0][t*65 + kk] = Wsrc0[e];
    Wl[1][t*65 + kk] = Wsrc1[e];
    Wl[2][t*65 + kk] = Wsrc2[e];
  }

  float p0 = 0.f;
  for (int jb = q; jb < JB; jb += 4)
    p0 += ws_ro[WS_Z0P + ((size_t)m * JB + jb) * 64 + k];
  part[tid] = p0;
  __syncthreads();
  if (tid < 64) {
    float a0 = b0[m*64 + k] + part[k] + part[64+k] + part[128+k] + part[192+k];
    hs[0][k] = fmaxf(a0, 0.f);
  }
  __syncthreads();

  #pragma unroll
  for (int l = 0; l < 3; l++) {
    float pp = 0.f;
    #pragma unroll
    for (int t0 = 0; t0 < 16; t0++) {
      int t = q*16 + t0;
      pp += hs[l][t] * Wl[l][t*65 + k];
    }
    part[tid] = pp;
    __syncthreads();
    if (tid < 64) {
      const float* bl = (l==0) ? b1 : (l==1) ? b2 : b3;
      float a = bl[m*64+k] + part[k] + part[64+k] + part[128+k] + part[192+k];
      hs[l+1][k] = fmaxf(a, 0.f);
    }
    __syncthreads();
  }

  if (tid < 64) {
    float w4k = W4[m*64 + k];
    float e = hs[3][k] * w4k;
    #pragma unroll
    for (int o = 1; o < 64; o <<= 1) e += __shfl_xor(e, o);
    if (k == 0) ws[WS_E + m] = e + b4[m];
    ds[k] = (hs[3][k] > 0.f) ? w4k : 0.f;
  }
  __syncthreads();

  #pragma unroll
  for (int l = 2; l >= 0; l--) {
    float pp = 0.f;
    int t = k;
    #pragma unroll
    for (int k0 = 0; k0 < 16; k0++) {
      int kk = q*16 + k0;
      pp += Wl[l][t*65 + kk] * ds[kk];
    }
    part[tid] = pp;
    __syncthreads();
    if (tid < 64) {
      float dh = part[k] + part[64+k] + part[128+k] + part[192+k];
      float dz = (hs[l][k] > 0.f) ? dh : 0.f;
      if (l == 0) ws[WS_DZ0 + m*64 + k] = dz;
      else        ds[k] = dz;
    }
    __syncthreads();
  }
}

// ---------------- K4: g[m][j] = (W0[m][j][:].dz0[m])*gamma[j]; 8-deep batches ----------------
__global__ void k_bwdx(const float4* __restrict__ W0, const float* __restrict__ gamma,
                       float* __restrict__ ws) {
  __shared__ float stats[2];
  __shared__ float dz[64];
  __shared__ float sa[4], sb[4];
  int tid = threadIdx.x;
  int m = blockIdx.y, blk = blockIdx.x;

  compute_mu_inv(ws, stats, tid);
  if (tid >= 64 && tid < 128) dz[tid - 64] = ws[WS_DZ0 + m*64 + (tid - 64)];
  __syncthreads();
  float mu = stats[0], inv = stats[1];

  int c = tid & 15;        // float4 column within row
  int g = tid >> 4;        // row group 0..15
  float4 d4 = ((const float4*)dz)[c];

  float sg = 0.f, sgx = 0.f;
  #pragma unroll
  for (int it = 0; it < 2; it++) {
    int jbase = blk * 256 + it * 128 + g;
    float4 wv[8];
    #pragma unroll
    for (int u = 0; u < 8; u++) {            // 8 independent loads in flight
      int j = jbase + u * 16;
      if (j < NX) wv[u] = W0[((size_t)m * NX + j) * 16 + c];
      else        wv[u] = {0.f, 0.f, 0.f, 0.f};
    }
    #pragma unroll
    for (int u = 0; u < 8; u++) {
      int j = jbase + u * 16;
      float dot = wv[u].x*d4.x + wv[u].y*d4.y + wv[u].z*d4.z + wv[u].w*d4.w;
      #pragma unroll
      for (int o = 1; o < 16; o <<= 1) dot += __shfl_xor(dot, o);
      if (c == 0 && j < NX) {
        float gg = dot * gamma[j];
        ws[WS_G + (size_t)m * NX + j] = gg;
        float xh = (ws[WS_XRAW + j] - mu) * inv;
        sg += gg; sgx += gg * xh;
      }
    }
  }
  #pragma unroll
  for (int o = 1; o < 64; o <<= 1) { sg += __shfl_xor(sg, o); sgx += __shfl_xor(sgx, o); }
  int w = tid >> 6, l = tid & 63;
  if (l == 0) { sa[w] = sg; sb[w] = sgx; }
  __syncthreads();
  if (tid == 0) {
    ws[WS_SGP  + m * NBX + blk] = sa[0] + sa[1] + sa[2] + sa[3];
    ws[WS_SGXP + m * NBX + blk] = sb[0] + sb[1] + sb[2] + sb[3];
  }
}

// ---------------- K5: mean force + variance + sigma + fused scatter ----------------
__global__ void k_mf(const int* __restrict__ idx, float* __restrict__ ws,
                     float* __restrict__ out) {
  __shared__ float stats[2];
  __shared__ float sSg[NM], sSgx[NM];
  __shared__ float sv[4];
  __shared__ float ssig;
  int tid = threadIdx.x;
  int w = tid >> 6, l = tid & 63;

  compute_mu_inv(ws, stats, tid);
  for (int m = w; m < NM; m += 4) {
    float a = 0.f, b = 0.f;
    #pragma unroll 2
    for (int bb = l; bb < NBX; bb += 64) { a += ws[WS_SGP + m*NBX + bb]; b += ws[WS_SGXP + m*NBX + bb]; }
    #pragma unroll
    for (int o = 1; o < 64; o <<= 1) { a += __shfl_xor(a, o); b += __shfl_xor(b, o); }
    if (l == 0) { sSg[m] = a * (1.f / NX); sSgx[m] = b * (1.f / NX); }
  }
  __syncthreads();
  float mu = stats[0], inv = stats[1];

  int i = blockIdx.x * 256 + tid;
  float v = 0.f, fm = 0.f;
  if (i < NCV) {
    float cph = ws[WS_XRAW + i], sph = ws[WS_XRAW + NCV + i];
    float xc = (cph - mu) * inv, xs = (sph - mu) * inv;
    float f[NM];
    #pragma unroll
    for (int m = 0; m < NM; m++) {
      float gc = ws[WS_G + (size_t)m * NX + i];
      float gs = ws[WS_G + (size_t)m * NX + NCV + i];
      float dxc = inv * (gc - sSg[m] - xc * sSgx[m]);
      float dxs = inv * (gs - sSg[m] - xs * sSgx[m]);
      float dE = dxc * (-sph) + dxs * cph;
      f[m] = -dE;
      fm += f[m];
    }
    fm *= (1.f / NM);
    float acc = 0.f;
    #pragma unroll
    for (int m = 0; m < NM; m++) { float d = f[m] - fm; acc += d * d; }
    v = acc * (1.f / (NM - 1));
  }
  #pragma unroll
  for (int o = 1; o < 64; o <<= 1) v += __shfl_xor(v, o);
  if (l == 0) sv[w] = v;
  __syncthreads();
  if (tid == 0) {
    atomicAdd(&ws[WS_VARSUM], sv[0] + sv[1] + sv[2] + sv[3]);
    __threadfence();
    unsigned int* tick = (unsigned int*)ws + WS_TICKET;
    unsigned int old = atomicAdd(tick, 1u);
    if (old == NB_MF - 1) {
      float tot = atomicAdd(&ws[WS_VARSUM], 0.0f);   // coherent read after all adds
      float md = sqrtf(tot * (1.f / NCV));
      float isw = (3.0f - md) / (3.0f - 2.0f);
      float fl = floorf(isw);
      float smooth = 0.5f * (1.f + cosf(3.14159265358979323846f * (1.f - isw)));
      float sigma = (fl > 0.f) ? 1.f : ((fl < 0.f) ? 0.f : smooth);
      float em = 0.f;
      #pragma unroll
      for (int m = 0; m < NM; m++) em += ws[WS_E + m];
      em *= (1.f / NM);
      out[0] = em * sigma;
      __hip_atomic_store(ws + WS_SIGMA, sigma, __ATOMIC_RELAXED, __HIP_MEMORY_SCOPE_AGENT);
      __hip_atomic_store((unsigned int*)ws + WS_FLAG, 1u, __ATOMIC_RELEASE, __HIP_MEMORY_SCOPE_AGENT);
    }
    while (__hip_atomic_load((unsigned int*)ws + WS_FLAG, __ATOMIC_ACQUIRE,
                             __HIP_MEMORY_SCOPE_AGENT) == 0u) {
      __builtin_amdgcn_s_sleep(8);
    }
    ssig = __hip_atomic_load(ws + WS_SIGMA, __ATOMIC_RELAXED, __HIP_MEMORY_SCOPE_AGENT);
  }
  __syncthreads();
  float sigma = ssig;

  if (i < NCV) {
    float d[12];
    #pragma unroll
    for (int r = 0; r < 12; r++) d[r] = ws[WS_DCV + r*NCV + i];   // coalesced
    int4 q4 = *(const int4*)(idx + i*4);
    float s = fm * sigma;
    float* fp = out + 1;
    atomicAdd(&fp[(size_t)q4.x*3 + 0], s*d[0]);
    atomicAdd(&fp[(size_t)q4.x*3 + 1], s*d[1]);
    atomicAdd(&fp[(size_t)q4.x*3 + 2], s*d[2]);
    atomicAdd(&fp[(size_t)q4.y*3 + 0], s*d[3]);
    atomicAdd(&fp[(size_t)q4.y*3 + 1], s*d[4]);
    atomicAdd(&fp[(size_t)q4.y*3 + 2], s*d[5]);
    atomicAdd(&fp[(size_t)q4.z*3 + 0], s*d[6]);
    atomicAdd(&fp[(size_t)q4.z*3 + 1], s*d[7]);
    atomicAdd(&fp[(size_t)q4.z*3 + 2], s*d[8]);
    atomicAdd(&fp[(size_t)q4.w*3 + 0], s*d[9]);
    atomicAdd(&fp[(size_t)q4.w*3 + 1], s*d[10]);
    atomicAdd(&fp[(size_t)q4.w*3 + 2], s*d[11]);
  }
}

extern "C" void kernel_launch(void* const* d_in, const int* in_sizes, int n_in,
                              void* d_out, int out_size, void* d_ws, size_t ws_size,
                              hipStream_t stream) {
  const float* pos   = (const float*)d_in[0];
  const float* box   = (const float*)d_in[1];
  const int*   idx   = (const int*)  d_in[2];
  const float* gamma = (const float*)d_in[3];
  const float* beta  = (const float*)d_in[4];
  const float* W0 = (const float*)d_in[5];
  const float* b0 = (const float*)d_in[6];
  const float* W1 = (const float*)d_in[7];
  const float* b1 = (const float*)d_in[8];
  const float* W2 = (const float*)d_in[9];
  const float* b2 = (const float*)d_in[10];
  const float* W3 = (const float*)d_in[11];
  const float* b3 = (const float*)d_in[12];
  const float* W4 = (const float*)d_in[13];
  const float* b4 = (const float*)d_in[14];
  float* ws  = (float*)d_ws;
  float* out = (float*)d_out;

  k_cv<<<NB_CV, 256, 0, stream>>>(pos, box, idx, ws, out);
  k_z0<<<dim3(JB, NM), 256, 0, stream>>>((const float4*)W0, gamma, beta, ws);
  k_mlp<<<NM, 256, 0, stream>>>(ws, b0, W1, b1, W2, b2, W3, b3, W4, b4, ws);
  k_bwdx<<<dim3(NBX, NM), 256, 0, stream>>>((const float4*)W0, gamma, ws);
  k_mf<<<NB_MF, 256, 0, stream>>>(idx, ws, out);
}

// Round 7
// 103.228 us; speedup vs baseline: 3.4976x; 1.4781x over previous
//
#include <hip/hip_runtime.h>
#include <math.h>

#define NCV   30000
#define NX    60000
#define NM    8
#define LN_EPSF 1e-5f
#define NFORCE 9000000      // force floats (3M x 3); d_out = [energy, forces...]

#define NB_CV 512           // k_cv grid
#define JB    96            // z0 slabs per model (625 rows each; 96*625 = 60000 exactly)
#define SLAB  625
#define NBX   235           // bwdx 256-row blocks per model
#define NB_MF 118           // k_mf grid (<=256 => co-resident => spin-safe)

// ---------------- workspace layout (float offsets) ----------------
#define WS_XRAW   0          // 60000  (cos | sin)
#define WS_DCV    60000      // 360000 dphi/dx TRANSPOSED [12][30000]
#define WS_G      420000     // 480000 dE/dxhat*gamma per model (8 x 60000)
#define WS_LNP    900000     // 1024: [512 sum_x | 512 sum_x2]
#define WS_Z0P    901024     // 8*96*64 = 49152 z0 partials
#define WS_DZ0    950176     // 512
#define WS_E      950688     // 8
#define WS_SGP    950696     // 8*235 = 1880
#define WS_SGXP   952576     // 1880
#define WS_VARSUM 954456     // 1
#define WS_TICKET 954457     // 1 (uint bits)
#define WS_SIGMA  954458     // 1
#define WS_FLAG   954459     // 1 (uint bits)

struct F3 { float x, y, z; };
__device__ __forceinline__ F3 f3sub(F3 a, F3 b){ return {a.x-b.x, a.y-b.y, a.z-b.z}; }
__device__ __forceinline__ F3 f3add(F3 a, F3 b){ return {a.x+b.x, a.y+b.y, a.z+b.z}; }
__device__ __forceinline__ F3 f3scale(F3 a, float s){ return {a.x*s, a.y*s, a.z*s}; }
__device__ __forceinline__ float f3dot(F3 a, F3 b){ return a.x*b.x + a.y*b.y + a.z*b.z; }
__device__ __forceinline__ F3 f3cross(F3 a, F3 b){
  return { a.y*b.z - a.z*b.y, a.z*b.x - a.x*b.z, a.x*b.y - a.y*b.x };
}

// reduce LN per-block partials -> out2[0]=mu, out2[1]=inv_std  (wave 0 only; caller syncs)
__device__ __forceinline__ void compute_mu_inv(const float* __restrict__ ws, float* out2, int tid) {
  if (tid < 64) {
    float a = 0.f, b = 0.f;
    #pragma unroll 4
    for (int k = tid; k < NB_CV; k += 64) { a += ws[WS_LNP + k]; b += ws[WS_LNP + NB_CV + k]; }
    #pragma unroll
    for (int o = 1; o < 64; o <<= 1) { a += __shfl_xor(a, o); b += __shfl_xor(b, o); }
    if (tid == 0) {
      float mu  = a * (1.f / NX);
      float var = b * (1.f / NX) - mu * mu;
      out2[0] = mu;
      out2[1] = 1.f / sqrtf(var + LN_EPSF);
    }
  }
}

// ---------------- K1: dihedrals + grads + LN partials + zero forces ----------------
__global__ void k_cv(const float* __restrict__ pos, const float* __restrict__ box,
                     const int* __restrict__ idx, float* __restrict__ ws,
                     float* __restrict__ out) {
  int tid = threadIdx.x;
  int gtid = blockIdx.x * 256 + tid;

  // zero forces (grid-stride float4) — k_cv is latency-bound, write BW here is free (R2-verified)
  {
    float4 z4 = {0.f, 0.f, 0.f, 0.f};
    float4* fz = (float4*)(out + 4);
    const int NF4 = (NFORCE - 4) / 4;
    for (int i = gtid; i < NF4; i += NB_CV * 256) fz[i] = z4;
    if (gtid == 0) {
      out[1] = 0.f; out[2] = 0.f; out[3] = 0.f; out[NFORCE] = 0.f;
      ws[WS_VARSUM] = 0.f;
      ((unsigned int*)ws)[WS_TICKET] = 0u;
      ((unsigned int*)ws)[WS_FLAG]   = 0u;
    }
  }

  float cx = 0.f, cx2 = 0.f;
  int i = gtid;
  if (i < NCV) {
    float bx = box[0], by = box[4], bz = box[8];
    int4 q4 = *(const int4*)(idx + i*4);
    int pidx[4] = {q4.x, q4.y, q4.z, q4.w};
    F3 p[4];
    #pragma unroll
    for (int a = 0; a < 4; a++) {
      int pi = pidx[a];
      float X = pos[(size_t)pi*3 + 0];
      float Y = pos[(size_t)pi*3 + 1];
      float Z = pos[(size_t)pi*3 + 2];
      X -= floorf(X / bx) * bx;
      Y -= floorf(Y / by) * by;
      Z -= floorf(Z / bz) * bz;
      p[a] = {X, Y, Z};
    }
    F3 b1 = f3sub(p[1], p[0]);
    F3 b2 = f3sub(p[2], p[1]);
    F3 b3 = f3sub(p[3], p[2]);
    F3 n1 = f3cross(b1, b2);
    F3 n2 = f3cross(b2, b3);
    float L = sqrtf(f3dot(b2, b2));
    F3 u = f3scale(b2, 1.f / L);
    F3 m1 = f3cross(n1, u);
    float yv = f3dot(m1, n2);
    float xv = f3dot(n1, n2);
    float h = sqrtf(xv*xv + yv*yv);
    float cphi = xv / h;
    float sphi = yv / h;

    // reverse mode, dphi = 1
    float invd = 1.f / (h*h);
    float dX = -yv * invd;
    float dY =  xv * invd;
    F3 dn1 = f3scale(n2, dX);
    F3 dn2 = f3scale(n1, dX);
    F3 dm1 = f3scale(n2, dY);
    dn2 = f3add(dn2, f3scale(m1, dY));
    dn1 = f3add(dn1, f3cross(u, dm1));
    F3 du = f3cross(dm1, n1);
    float ud = f3dot(u, du);
    F3 db2 = f3scale(f3sub(du, f3scale(u, ud)), 1.f / L);
    db2 = f3add(db2, f3cross(b3, dn2));
    F3 db3 = f3cross(dn2, b2);
    F3 db1 = f3cross(b2, dn1);
    db2 = f3add(db2, f3cross(dn1, b1));

    F3 g0 = f3scale(db1, -1.f);
    F3 g1 = f3sub(db1, db2);
    F3 g2 = f3sub(db2, db3);
    F3 g3 = db3;

    ws[WS_XRAW + i]       = cphi;
    ws[WS_XRAW + NCV + i] = sphi;
    ws[WS_DCV + 0*NCV  + i] = g0.x; ws[WS_DCV + 1*NCV  + i] = g0.y; ws[WS_DCV + 2*NCV  + i] = g0.z;
    ws[WS_DCV + 3*NCV  + i] = g1.x; ws[WS_DCV + 4*NCV  + i] = g1.y; ws[WS_DCV + 5*NCV  + i] = g1.z;
    ws[WS_DCV + 6*NCV  + i] = g2.x; ws[WS_DCV + 7*NCV  + i] = g2.y; ws[WS_DCV + 8*NCV  + i] = g2.z;
    ws[WS_DCV + 9*NCV  + i] = g3.x; ws[WS_DCV + 10*NCV + i] = g3.y; ws[WS_DCV + 11*NCV + i] = g3.z;

    cx  = cphi + sphi;
    cx2 = cphi*cphi + sphi*sphi;
  }

  #pragma unroll
  for (int o = 1; o < 64; o <<= 1) { cx += __shfl_xor(cx, o); cx2 += __shfl_xor(cx2, o); }
  __shared__ float sa[4], sb[4];
  int w = tid >> 6, l = tid & 63;
  if (l == 0) { sa[w] = cx; sb[w] = cx2; }
  __syncthreads();
  if (tid == 0) {
    ws[WS_LNP + blockIdx.x]         = sa[0] + sa[1] + sa[2] + sa[3];
    ws[WS_LNP + NB_CV + blockIdx.x] = sb[0] + sb[1] + sb[2] + sb[3];
  }
}

// ---------------- K2: z0 partials; 625-row slabs, 768 equal blocks; R2-proven loop ----------------
__global__ __launch_bounds__(256, 2)
void k_z0(const float4* __restrict__ W0, const float* __restrict__ gamma,
          const float* __restrict__ beta, float* __restrict__ ws) {
  __shared__ float stats[2];
  __shared__ float yl[SLAB];
  __shared__ float red[4][16][4];
  int tid = threadIdx.x;
  int jb = blockIdx.x, m = blockIdx.y;
  int j0 = jb * SLAB;           // 96*625 = 60000: no tail, no bounds checks

  compute_mu_inv(ws, stats, tid);
  __syncthreads();
  float mu = stats[0], inv = stats[1];
  for (int jj = tid; jj < SLAB; jj += 256) {
    int gj = j0 + jj;
    yl[jj] = (ws[WS_XRAW + gj] - mu) * inv * gamma[gj] + beta[gj];
  }
  __syncthreads();

  int k4 = tid & 15;     // float4 column of the 64-wide row
  int r  = tid >> 4;     // row phase 0..15
  const float4* Wm = W0 + (size_t)m * NX * 16;
  float4 acc = {0.f, 0.f, 0.f, 0.f};
  #pragma unroll 4
  for (int j = r; j < SLAB; j += 16) {          // scalar wv per iter: regs, no scratch
    float y = yl[j];
    float4 wv = Wm[(size_t)(j0 + j) * 16 + k4];
    acc.x += y * wv.x; acc.y += y * wv.y; acc.z += y * wv.z; acc.w += y * wv.w;
  }
  #pragma unroll
  for (int o = 16; o <= 32; o <<= 1) {
    acc.x += __shfl_xor(acc.x, o); acc.y += __shfl_xor(acc.y, o);
    acc.z += __shfl_xor(acc.z, o); acc.w += __shfl_xor(acc.w, o);
  }
  int w = tid >> 6, l = tid & 63;
  if (l < 16) {
    red[w][l][0] = acc.x; red[w][l][1] = acc.y; red[w][l][2] = acc.z; red[w][l][3] = acc.w;
  }
  __syncthreads();
  if (tid < 64) {
    int kk4 = tid & 15, c = tid >> 4;
    float v = red[0][kk4][c] + red[1][kk4][c] + red[2][kk4][c] + red[3][kk4][c];
    ws[WS_Z0P + ((size_t)m * JB + jb) * 64 + kk4 * 4 + c] = v;
  }
}

// ---------------- K3: tiny MLP fwd+bwd per model, LDS-staged weights ----------------
__global__ void k_mlp(const float* __restrict__ ws_ro, const float* __restrict__ b0,
                      const float* __restrict__ W1, const float* __restrict__ b1,
                      const float* __restrict__ W2, const float* __restrict__ b2,
                      const float* __restrict__ W3, const float* __restrict__ b3,
                      const float* __restrict__ W4, const float* __restrict__ b4,
                      float* __restrict__ ws) {
  int m = blockIdx.x;
  int tid = threadIdx.x;
  int k = tid & 63, q = tid >> 6;           // q = t-quarter 0..3
  __shared__ float Wl[3][64*65];            // 65-stride pad: conflict-free both directions
  __shared__ float hs[4][64];
  __shared__ float part[256];
  __shared__ float ds[64];

  const float* Wsrc0 = W1 + m*4096;
  const float* Wsrc1 = W2 + m*4096;
  const float* Wsrc2 = W3 + m*4096;
  for (int e = tid; e < 4096; e += 256) {
    int t = e >> 6, kk = e & 63;
    Wl[0][t*65 + kk] = Wsrc0[e];
    Wl[1][t*65 + kk] = Wsrc1[e];
    Wl[2][t*65 + kk] = Wsrc2[e];
  }

  float p0 = 0.f;
  for (int jb = q; jb < JB; jb += 4)
    p0 += ws_ro[WS_Z0P + ((size_t)m * JB + jb) * 64 + k];
  part[tid] = p0;
  __syncthreads();
  if (tid < 64) {
    float a0 = b0[m*64 + k] + part[k] + part[64+k] + part[128+k] + part[192+k];
    hs[0][k] = fmaxf(a0, 0.f);
  }
  __syncthreads();

  #pragma unroll
  for (int l = 0; l < 3; l++) {
    float pp = 0.f;
    #pragma unroll
    for (int t0 = 0; t0 < 16; t0++) {
      int t = q*16 + t0;
      pp += hs[l][t] * Wl[l][t*65 + k];
    }
    part[tid] = pp;
    __syncthreads();
    if (tid < 64) {
      const float* bl = (l==0) ? b1 : (l==1) ? b2 : b3;
      float a = bl[m*64+k] + part[k] + part[64+k] + part[128+k] + part[192+k];
      hs[l+1][k] = fmaxf(a, 0.f);
    }
    __syncthreads();
  }

  if (tid < 64) {
    float w4k = W4[m*64 + k];
    float e = hs[3][k] * w4k;
    #pragma unroll
    for (int o = 1; o < 64; o <<= 1) e += __shfl_xor(e, o);
    if (k == 0) ws[WS_E + m] = e + b4[m];
    ds[k] = (hs[3][k] > 0.f) ? w4k : 0.f;
  }
  __syncthreads();

  #pragma unroll
  for (int l = 2; l >= 0; l--) {
    float pp = 0.f;
    int t = k;
    #pragma unroll
    for (int k0 = 0; k0 < 16; k0++) {
      int kk = q*16 + k0;
      pp += Wl[l][t*65 + kk] * ds[kk];
    }
    part[tid] = pp;
    __syncthreads();
    if (tid < 64) {
      float dh = part[k] + part[64+k] + part[128+k] + part[192+k];
      float dz = (hs[l][k] > 0.f) ? dh : 0.f;
      if (l == 0) ws[WS_DZ0 + m*64 + k] = dz;
      else        ds[k] = dz;
    }
    __syncthreads();
  }
}

// ---------------- K4: g[m][j] = (W0[m][j][:].dz0[m])*gamma[j]; clamped 4-deep batches ----------------
__global__ __launch_bounds__(256, 2)
void k_bwdx(const float4* __restrict__ W0, const float* __restrict__ gamma,
            float* __restrict__ ws) {
  __shared__ float stats[2];
  __shared__ float dz[64];
  __shared__ float sa[4], sb[4];
  int tid = threadIdx.x;
  int m = blockIdx.y, blk = blockIdx.x;

  compute_mu_inv(ws, stats, tid);
  if (tid >= 64 && tid < 128) dz[tid - 64] = ws[WS_DZ0 + m*64 + (tid - 64)];
  __syncthreads();
  float mu = stats[0], inv = stats[1];

  int c = tid & 15;        // float4 column within row
  int g = tid >> 4;        // row group 0..15
  float4 d4 = ((const float4*)dz)[c];

  float sg = 0.f, sgx = 0.f;
  #pragma unroll
  for (int it = 0; it < 4; it++) {
    int jbase = blk * 256 + it * 64 + g;
    float4 wv[4];
    #pragma unroll
    for (int u = 0; u < 4; u++) {
      int j = jbase + u * 16;
      int jc = min(j, NX - 1);               // unconditional init -> stays in registers
      wv[u] = W0[((size_t)m * NX + jc) * 16 + c];
    }
    #pragma unroll
    for (int u = 0; u < 4; u++) {
      int j = jbase + u * 16;
      float dot = wv[u].x*d4.x + wv[u].y*d4.y + wv[u].z*d4.z + wv[u].w*d4.w;
      #pragma unroll
      for (int o = 1; o < 16; o <<= 1) dot += __shfl_xor(dot, o);
      if (c == 0 && j < NX) {
        float gg = dot * gamma[j];
        ws[WS_G + (size_t)m * NX + j] = gg;
        float xh = (ws[WS_XRAW + j] - mu) * inv;
        sg += gg; sgx += gg * xh;
      }
    }
  }
  #pragma unroll
  for (int o = 1; o < 64; o <<= 1) { sg += __shfl_xor(sg, o); sgx += __shfl_xor(sgx, o); }
  int w = tid >> 6, l = tid & 63;
  if (l == 0) { sa[w] = sg; sb[w] = sgx; }
  __syncthreads();
  if (tid == 0) {
    ws[WS_SGP  + m * NBX + blk] = sa[0] + sa[1] + sa[2] + sa[3];
    ws[WS_SGXP + m * NBX + blk] = sb[0] + sb[1] + sb[2] + sb[3];
  }
}

// ---------------- K5: mean force + variance + sigma + fused scatter ----------------
__global__ void k_mf(const int* __restrict__ idx, float* __restrict__ ws,
                     float* __restrict__ out) {
  __shared__ float stats[2];
  __shared__ float sSg[NM], sSgx[NM];
  __shared__ float sv[4];
  __shared__ float ssig;
  int tid = threadIdx.x;
  int w = tid >> 6, l = tid & 63;

  compute_mu_inv(ws, stats, tid);
  for (int m = w; m < NM; m += 4) {
    float a = 0.f, b = 0.f;
    #pragma unroll 2
    for (int bb = l; bb < NBX; bb += 64) { a += ws[WS_SGP + m*NBX + bb]; b += ws[WS_SGXP + m*NBX + bb]; }
    #pragma unroll
    for (int o = 1; o < 64; o <<= 1) { a += __shfl_xor(a, o); b += __shfl_xor(b, o); }
    if (l == 0) { sSg[m] = a * (1.f / NX); sSgx[m] = b * (1.f / NX); }
  }
  __syncthreads();
  float mu = stats[0], inv = stats[1];

  int i = blockIdx.x * 256 + tid;
  float v = 0.f, fm = 0.f;
  if (i < NCV) {
    float cph = ws[WS_XRAW + i], sph = ws[WS_XRAW + NCV + i];
    float xc = (cph - mu) * inv, xs = (sph - mu) * inv;
    float f[NM];
    #pragma unroll
    for (int m = 0; m < NM; m++) {
      float gc = ws[WS_G + (size_t)m * NX + i];
      float gs = ws[WS_G + (size_t)m * NX + NCV + i];
      float dxc = inv * (gc - sSg[m] - xc * sSgx[m]);
      float dxs = inv * (gs - sSg[m] - xs * sSgx[m]);
      float dE = dxc * (-sph) + dxs * cph;
      f[m] = -dE;
      fm += f[m];
    }
    fm *= (1.f / NM);
    float acc = 0.f;
    #pragma unroll
    for (int m = 0; m < NM; m++) { float d = f[m] - fm; acc += d * d; }
    v = acc * (1.f / (NM - 1));
  }
  #pragma unroll
  for (int o = 1; o < 64; o <<= 1) v += __shfl_xor(v, o);
  if (l == 0) sv[w] = v;
  __syncthreads();
  if (tid == 0) {
    atomicAdd(&ws[WS_VARSUM], sv[0] + sv[1] + sv[2] + sv[3]);
    __threadfence();
    unsigned int* tick = (unsigned int*)ws + WS_TICKET;
    unsigned int old = atomicAdd(tick, 1u);
    if (old == NB_MF - 1) {
      float tot = atomicAdd(&ws[WS_VARSUM], 0.0f);   // coherent read after all adds
      float md = sqrtf(tot * (1.f / NCV));
      float isw = (3.0f - md) / (3.0f - 2.0f);
      float fl = floorf(isw);
      float smooth = 0.5f * (1.f + cosf(3.14159265358979323846f * (1.f - isw)));
      float sigma = (fl > 0.f) ? 1.f : ((fl < 0.f) ? 0.f : smooth);
      float em = 0.f;
      #pragma unroll
      for (int m = 0; m < NM; m++) em += ws[WS_E + m];
      em *= (1.f / NM);
      out[0] = em * sigma;
      __hip_atomic_store(ws + WS_SIGMA, sigma, __ATOMIC_RELAXED, __HIP_MEMORY_SCOPE_AGENT);
      __hip_atomic_store((unsigned int*)ws + WS_FLAG, 1u, __ATOMIC_RELEASE, __HIP_MEMORY_SCOPE_AGENT);
    }
    while (__hip_atomic_load((unsigned int*)ws + WS_FLAG, __ATOMIC_ACQUIRE,
                             __HIP_MEMORY_SCOPE_AGENT) == 0u) {
      __builtin_amdgcn_s_sleep(8);
    }
    ssig = __hip_atomic_load(ws + WS_SIGMA, __ATOMIC_RELAXED, __HIP_MEMORY_SCOPE_AGENT);
  }
  __syncthreads();
  float sigma = ssig;

  if (i < NCV) {
    float d[12];
    #pragma unroll
    for (int r = 0; r < 12; r++) d[r] = ws[WS_DCV + r*NCV + i];   // coalesced
    int4 q4 = *(const int4*)(idx + i*4);
    float s = fm * sigma;
    float* fp = out + 1;
    atomicAdd(&fp[(size_t)q4.x*3 + 0], s*d[0]);
    atomicAdd(&fp[(size_t)q4.x*3 + 1], s*d[1]);
    atomicAdd(&fp[(size_t)q4.x*3 + 2], s*d[2]);
    atomicAdd(&fp[(size_t)q4.y*3 + 0], s*d[3]);
    atomicAdd(&fp[(size_t)q4.y*3 + 1], s*d[4]);
    atomicAdd(&fp[(size_t)q4.y*3 + 2], s*d[5]);
    atomicAdd(&fp[(size_t)q4.z*3 + 0], s*d[6]);
    atomicAdd(&fp[(size_t)q4.z*3 + 1], s*d[7]);
    atomicAdd(&fp[(size_t)q4.z*3 + 2], s*d[8]);
    atomicAdd(&fp[(size_t)q4.w*3 + 0], s*d[9]);
    atomicAdd(&fp[(size_t)q4.w*3 + 1], s*d[10]);
    atomicAdd(&fp[(size_t)q4.w*3 + 2], s*d[11]);
  }
}

extern "C" void kernel_launch(void* const* d_in, const int* in_sizes, int n_in,
                              void* d_out, int out_size, void* d_ws, size_t ws_size,
                              hipStream_t stream) {
  const float* pos   = (const float*)d_in[0];
  const float* box   = (const float*)d_in[1];
  const int*   idx   = (const int*)  d_in[2];
  const float* gamma = (const float*)d_in[3];
  const float* beta  = (const float*)d_in[4];
  const float* W0 = (const float*)d_in[5];
  const float* b0 = (const float*)d_in[6];
  const float* W1 = (const float*)d_in[7];
  const float* b1 = (const float*)d_in[8];
  const float* W2 = (const float*)d_in[9];
  const float* b2 = (const float*)d_in[10];
  const float* W3 = (const float*)d_in[11];
  const float* b3 = (const float*)d_in[12];
  const float* W4 = (const float*)d_in[13];
  const float* b4 = (const float*)d_in[14];
  float* ws  = (float*)d_ws;
  float* out = (float*)d_out;

  k_cv<<<NB_CV, 256, 0, stream>>>(pos, box, idx, ws, out);
  k_z0<<<dim3(JB, NM), 256, 0, stream>>>((const float4*)W0, gamma, beta, ws);
  k_mlp<<<NM, 256, 0, stream>>>(ws, b0, W1, b1, W2, b2, W3, b3, W4, b4, ws);
  k_bwdx<<<dim3(NBX, NM), 256, 0, stream>>>((const float4*)W0, gamma, ws);
  k_mf<<<NB_MF, 256, 0, stream>>>(idx, ws, out);
}